// Round 4
// baseline (165.259 us; speedup 1.0000x reference)
//
#include <hip/hip_runtime.h>
#include <math.h>

#define TB 256
#define GRID 512       // 2 blocks/CU nominal; capacity >= 4/CU => 2x co-residency margin
#define S_LEN 8000
#define B_N 128
#define TPB 8          // tiles (256-row chunks) per block; 512 blocks x 8 = 4096 tiles

// ---------------- device helpers ----------------

__device__ __forceinline__ void compute_ln(const float* __restrict__ xp,
                                           const float* __restrict__ lg, const float* __restrict__ lb,
                                           float* y) {
  float v[9];
  float m = 0.f;
#pragma unroll
  for (int j = 0; j < 9; ++j) { v[j] = xp[j]; m += v[j]; }
  m *= (1.f / 9.f);
  float var = 0.f;
#pragma unroll
  for (int j = 0; j < 9; ++j) { float d = v[j] - m; var += d * d; }
  var *= (1.f / 9.f);
  float rs = rsqrtf(var + 1e-6f);
#pragma unroll
  for (int j = 0; j < 9; ++j) y[j] = (v[j] - m) * rs * lg[j] + lb[j];
}

__device__ __forceinline__ void matvec89(const float* __restrict__ W, const float* __restrict__ bias,
                                         const float* __restrict__ y, float* out) {
#pragma unroll
  for (int i = 0; i < 8; ++i) {
    float a = bias[i];
#pragma unroll
    for (int j = 0; j < 9; ++j) a += W[i * 9 + j] * y[j];
    out[i] = a;
  }
}

__device__ __forceinline__ float head_scale(const float* q, const float* v, const float* bindS,
                                            int h, float maskv) {
  float q0 = q[2 * h], q1 = q[2 * h + 1];
  float v0 = v[2 * h], v1 = v[2 * h + 1];
  float B0 = bindS[2 * h], B1 = bindS[2 * h + 1];
  // HD=2: real 2-pt FFT self-conjugate -> unbinding == circular conv
  float vp0 = B0 * q0 + B1 * q1;
  float vp1 = B0 * q1 + B1 * q0;
  float num = v0 * vp0 + v1 * vp1;
  float na = fmaxf(sqrtf(v0 * v0 + v1 * v1), 1e-8f);
  float nb = fmaxf(sqrtf(vp0 * vp0 + vp1 * vp1), 1e-8f);
  float sc = num / (na * nb);
  sc += (1.f - maskv) * (-1e9f);
  return sc;
}

__device__ __forceinline__ void stage_x(const float* __restrict__ x, const float* __restrict__ pos,
                                        int b, int s0, int nrow, float4* xs4, int tid) {
  const int n4 = (nrow * 9) >> 2;   // nrow in {256,64}: nrow*9 divisible by 4
  const float4* xb4 = (const float4*)(x + ((size_t)b * S_LEN + s0) * 9);
  const float4* pb4 = (const float4*)(pos + (size_t)s0 * 9);
  for (int i = tid; i < n4; i += TB) {
    float4 a = xb4[i], p = pb4[i];
    xs4[i] = make_float4(a.x + p.x, a.y + p.y, a.z + p.z, a.w + p.w);
  }
}

// device-scope grid barrier: release fence -> arrive -> spin -> acquire fence.
// __threadfence() on gfx950 emits L2 writeback/invalidate (cross-XCD safe, G16).
__device__ __forceinline__ void grid_barrier(unsigned* ctr) {
  __syncthreads();
  if (threadIdx.x == 0) {
    __threadfence();
    atomicAdd(ctr, 1u);
    while (__hip_atomic_load(ctr, __ATOMIC_RELAXED, __HIP_MEMORY_SCOPE_AGENT) < (unsigned)GRID)
      __builtin_amdgcn_s_sleep(2);
    __threadfence();
  }
  __syncthreads();
}

// ---------------- init: zero barrier counters each launch ----------------
__global__ void k_init(unsigned* __restrict__ ctrs) {
  if (threadIdx.x < 2) ctrs[threadIdx.x] = 0u;
}

// ---------------- fused persistent kernel ----------------
__global__ __launch_bounds__(TB, 4) void k_fused(
    const float* __restrict__ x, const float* __restrict__ mask, const float* __restrict__ pos,
    const float* __restrict__ lng, const float* __restrict__ lnb,
    const float* __restrict__ Wq, const float* __restrict__ bq,
    const float* __restrict__ Wk, const float* __restrict__ bk,
    const float* __restrict__ Wv, const float* __restrict__ bv,
    const float* __restrict__ W2, const float* __restrict__ b2,
    const float* __restrict__ Wo, const float* __restrict__ bo,
    float* __restrict__ bindP, float* __restrict__ sumP,
    unsigned* __restrict__ ctrs, float* __restrict__ out) {
  __shared__ float4 xs4[TB * 9 / 4];   // one 256-row tile of x+pos
  __shared__ float wqS[72], wkS[72], wvS[72], w2S[72];
  __shared__ float bqS[8], bkS[8], bvS[8], b2S[9], woS[9], lgS[9], lbS[9];
  __shared__ float boS;
  __shared__ float red[4 * 8];
  __shared__ float bindS[8], invDS[4];
  float* xs = (float*)xs4;

  const int tid = threadIdx.x, bid = blockIdx.x;
  const int b = bid >> 2;              // batch (0..127)
  const int c0 = (bid & 3) * TPB;      // first chunk index (0,8,16,24)
  const int wave = tid >> 6, lane = tid & 63;

  if (tid < 72) { wqS[tid] = Wq[tid]; wkS[tid] = Wk[tid]; wvS[tid] = Wv[tid]; w2S[tid] = W2[tid]; }
  if (tid < 8)  { bqS[tid] = bq[tid]; bkS[tid] = bk[tid]; bvS[tid] = bv[tid]; }
  if (tid < 9)  { lgS[tid] = lng[tid]; lbS[tid] = lnb[tid]; b2S[tid] = b2[tid]; woS[tid] = Wo[tid]; }
  if (tid == 0) { boS = bo[0]; }
  // published by the first __syncthreads below

  // ---------------- phase 1: bind accumulation ----------------
  float acc[8];
#pragma unroll
  for (int i = 0; i < 8; ++i) acc[i] = 0.f;

#pragma unroll
  for (int t = 0; t < TPB; ++t) {
    const int cx = c0 + t, s0 = cx * TB;
    const int nrow = min(TB, S_LEN - s0);
    __syncthreads();
    stage_x(x, pos, b, s0, nrow, xs4, tid);
    __syncthreads();
    if (tid < nrow) {
      float y[9];
      compute_ln(&xs[tid * 9], lgS, lbS, y);
      float kk[8], vv[8];
      matvec89(wkS, bkS, y, kk);
      matvec89(wvS, bvS, y, vv);
#pragma unroll
      for (int h = 0; h < 4; ++h) {
        float k0 = kk[2 * h], k1 = kk[2 * h + 1];
        float v0 = vv[2 * h], v1 = vv[2 * h + 1];
        acc[2 * h]     += k0 * v0 + k1 * v1;
        acc[2 * h + 1] += k0 * v1 + k1 * v0;
      }
    }
  }
#pragma unroll
  for (int i = 0; i < 8; ++i) {
#pragma unroll
    for (int off = 32; off > 0; off >>= 1) acc[i] += __shfl_down(acc[i], off, 64);
  }
  __syncthreads();
  if (lane == 0) {
#pragma unroll
    for (int i = 0; i < 8; ++i) red[wave * 8 + i] = acc[i];
  }
  __syncthreads();
  if (tid < 8) {
    bindP[bid * 8 + tid] = red[tid] + red[8 + tid] + red[16 + tid] + red[24 + tid];
  }

  grid_barrier(&ctrs[0]);

  // ---------------- phase 2: e numerators (kept in regs) + denom partials ----------------
  if (tid < 8) {   // reduce the 4 blocks of this batch
    float s = 0.f;
#pragma unroll
    for (int j = 0; j < 4; ++j) s += bindP[((b << 2) + j) * 8 + tid];
    bindS[tid] = s;
  }

  float e[TPB][4];
  float esum[4] = {0.f, 0.f, 0.f, 0.f};
#pragma unroll
  for (int t = 0; t < TPB; ++t) {
    const int cx = c0 + t, s0 = cx * TB;
    const int nrow = min(TB, S_LEN - s0);
    __syncthreads();   // also publishes bindS on t==0
    stage_x(x, pos, b, s0, nrow, xs4, tid);
    __syncthreads();
#pragma unroll
    for (int h = 0; h < 4; ++h) e[t][h] = 0.f;
    if (tid < nrow) {
      const int s = s0 + tid;
      float y[9];
      compute_ln(&xs[tid * 9], lgS, lbS, y);
      float qq[8], vv[8];
      matvec89(wqS, bqS, y, qq);
      matvec89(wvS, bvS, y, vv);
#pragma unroll
      for (int h = 0; h < 4; ++h) {
        float m = mask[((size_t)(b * 4 + h)) * S_LEN + s];
        e[t][h] = expf(head_scale(qq, vv, bindS, h, m));  // |cos sim|<=1: no max-sub
        esum[h] += e[t][h];
      }
    }
  }
#pragma unroll
  for (int h = 0; h < 4; ++h) {
#pragma unroll
    for (int off = 32; off > 0; off >>= 1) esum[h] += __shfl_down(esum[h], off, 64);
  }
  __syncthreads();
  if (lane == 0) {
#pragma unroll
    for (int h = 0; h < 4; ++h) red[wave * 4 + h] = esum[h];
  }
  __syncthreads();
  if (tid < 4) {
    sumP[bid * 4 + tid] = red[tid] + red[4 + tid] + red[8 + tid] + red[12 + tid];
  }

  grid_barrier(&ctrs[1]);

  // ---------------- phase 3: output ----------------
  if (tid < 4) {
    float s = 0.f;
#pragma unroll
    for (int j = 0; j < 4; ++j) s += sumP[((b << 2) + j) * 4 + tid];
    invDS[tid] = 1.f / s;
  }

#pragma unroll
  for (int t = 0; t < TPB; ++t) {
    const int cx = c0 + t, s0 = cx * TB;
    const int nrow = min(TB, S_LEN - s0);
    __syncthreads();   // also publishes invDS on t==0
    stage_x(x, pos, b, s0, nrow, xs4, tid);
    __syncthreads();
    if (tid < nrow) {
      const int s = s0 + tid;
      float y[9];
      compute_ln(&xs[tid * 9], lgS, lbS, y);
      float vv[8];
      matvec89(wvS, bvS, y, vv);

      float w0 = e[t][0] * invDS[0], w1 = e[t][1] * invDS[1];
      float w2 = e[t][2] * invDS[2], w3 = e[t][3] * invDS[3];
      float attn[8] = {w0 * vv[0], w0 * vv[1], w1 * vv[2], w1 * vv[3],
                       w2 * vv[4], w2 * vv[5], w3 * vv[6], w3 * vv[7]};

      float o = boS;
#pragma unroll
      for (int i = 0; i < 9; ++i) {
        float tt = b2S[i];
#pragma unroll
        for (int j = 0; j < 8; ++j) tt += w2S[i * 8 + j] * attn[j];
        float g = 0.5f * tt * (1.f + erff(tt * 0.70710678118654752f));
        o += woS[i] * (g + y[i]);
      }
      out[(size_t)b * S_LEN + s] = o;
    }
  }
}

// ---------------- launch ----------------

extern "C" void kernel_launch(void* const* d_in, const int* in_sizes, int n_in,
                              void* d_out, int out_size, void* d_ws, size_t ws_size,
                              hipStream_t stream) {
  const float* x    = (const float*)d_in[0];
  const float* mask = (const float*)d_in[1];
  const float* pos  = (const float*)d_in[2];
  const float* lng  = (const float*)d_in[3];
  const float* lnb  = (const float*)d_in[4];
  const float* Wq   = (const float*)d_in[5];
  const float* bq   = (const float*)d_in[6];
  const float* Wk   = (const float*)d_in[7];
  const float* bk   = (const float*)d_in[8];
  const float* Wv   = (const float*)d_in[9];
  const float* bv   = (const float*)d_in[10];
  // d_in[11] = W1, d_in[12] = b1  (dead in reference)
  const float* W2   = (const float*)d_in[13];
  const float* b2   = (const float*)d_in[14];
  const float* Wo   = (const float*)d_in[15];
  const float* bo   = (const float*)d_in[16];
  float* out = (float*)d_out;

  unsigned* ctrs  = (unsigned*)d_ws;                 // 2 barrier counters
  float*    bindP = (float*)d_ws + 16;               // GRID*8 floats
  float*    sumP  = (float*)d_ws + 16 + GRID * 8;    // GRID*4 floats

  k_init<<<1, 64, 0, stream>>>(ctrs);
  k_fused<<<GRID, TB, 0, stream>>>(x, mask, pos, lng, lnb, Wq, bq, Wk, bk, Wv, bv,
                                   W2, b2, Wo, bo, bindP, sumP, ctrs, out);
}

// Round 5
// 140.173 us; speedup vs baseline: 1.1790x; 1.1790x over previous
//
#include <hip/hip_runtime.h>
#include <math.h>

#define TB 256
#define S_LEN 8000
#define B_N 128
#define BPB 8            // sibling blocks per batch
#define TPB 4            // 256-row tiles per block (8*4*256 >= 8000)
#define GRID (B_N * BPB) // 1024
#define CTRW 16          // uints per counter slot (64B padding)

// ---------------- device helpers ----------------

__device__ __forceinline__ void matvec89(const float* __restrict__ W, const float* __restrict__ bias,
                                         const float* __restrict__ y, float* out) {
#pragma unroll
  for (int i = 0; i < 8; ++i) {
    float a = bias[i];
#pragma unroll
    for (int j = 0; j < 9; ++j) a += W[i * 9 + j] * y[j];
    out[i] = a;
  }
}

__device__ __forceinline__ float head_scale(const float* q, const float* v, const float* bindS,
                                            int h, float maskv) {
  float q0 = q[2 * h], q1 = q[2 * h + 1];
  float v0 = v[2 * h], v1 = v[2 * h + 1];
  float B0 = bindS[2 * h], B1 = bindS[2 * h + 1];
  // HD=2: real 2-pt FFT self-conjugate -> unbinding == circular conv
  float vp0 = B0 * q0 + B1 * q1;
  float vp1 = B0 * q1 + B1 * q0;
  float num = v0 * vp0 + v1 * vp1;
  float na = fmaxf(sqrtf(v0 * v0 + v1 * v1), 1e-8f);
  float nb = fmaxf(sqrtf(vp0 * vp0 + vp1 * vp1), 1e-8f);
  float sc = num / (na * nb);
  sc += (1.f - maskv) * (-1e9f);
  return sc;
}

// per-batch barrier: publish done (relaxed agent RMW), poll until all BPB arrived.
// Data crossing the barrier is written/read with relaxed AGENT atomics (sc1,
// served at LLC) and ordered by the vmcnt-draining __syncthreads before the RMW
// -> no threadfence / L2 writeback anywhere.
__device__ __forceinline__ void batch_barrier(unsigned* ctr, int tid) {
  __syncthreads();  // drains vmcnt: partial stores are at LLC before the add
  if (tid == 0) {
    __hip_atomic_fetch_add(ctr, 1u, __ATOMIC_RELAXED, __HIP_MEMORY_SCOPE_AGENT);
    while (__hip_atomic_load(ctr, __ATOMIC_ACQUIRE, __HIP_MEMORY_SCOPE_AGENT) < (unsigned)BPB)
      __builtin_amdgcn_s_sleep(8);
  }
  __syncthreads();
}

// ---------------- fused kernel ----------------
__global__ __launch_bounds__(TB, 4) void k_fused(
    const float* __restrict__ x, const float* __restrict__ mask, const float* __restrict__ pos,
    const float* __restrict__ lng, const float* __restrict__ lnb,
    const float* __restrict__ Wq, const float* __restrict__ bq,
    const float* __restrict__ Wk, const float* __restrict__ bk,
    const float* __restrict__ Wv, const float* __restrict__ bv,
    const float* __restrict__ W2, const float* __restrict__ b2,
    const float* __restrict__ Wo, const float* __restrict__ bo,
    unsigned* __restrict__ ctr1, unsigned* __restrict__ ctr2,
    float* __restrict__ bindP, float* __restrict__ sumPB,
    float* __restrict__ out) {
  __shared__ float ys[TPB][TB * 9];   // LN output, 36864 B -> 4 blocks/CU
  __shared__ float wqS[72], wkS[72], wvS[72], w2S[72];
  __shared__ float bqS[8], bkS[8], bvS[8], b2S[9], woS[9], lgS[9], lbS[9];
  __shared__ float boS;
  __shared__ float red[4 * 8];
  __shared__ float bindS[8], invDS[4];

  const int tid = threadIdx.x, bid = blockIdx.x;
  const int b = bid >> 3;            // batch 0..127
  const int t0 = (bid & 7) * TPB;    // first tile of this block
  const int wave = tid >> 6, lane = tid & 63;

  if (tid < 72) { wqS[tid] = Wq[tid]; wkS[tid] = Wk[tid]; wvS[tid] = Wv[tid]; w2S[tid] = W2[tid]; }
  if (tid < 8)  { bqS[tid] = bq[tid]; bkS[tid] = bk[tid]; bvS[tid] = bv[tid]; }
  if (tid < 9)  { lgS[tid] = lng[tid]; lbS[tid] = lnb[tid]; b2S[tid] = b2[tid]; woS[tid] = Wo[tid]; }
  if (tid == 0) { boS = bo[0]; }

  int nrowA[TPB];
#pragma unroll
  for (int t = 0; t < TPB; ++t) nrowA[t] = min(TB, S_LEN - (t0 + t) * TB);

  // ---- phase 0: stage x+pos once, LayerNorm in place ----
#pragma unroll
  for (int t = 0; t < TPB; ++t) {
    const int s0 = (t0 + t) * TB;
    const int n4 = (nrowA[t] * 9) >> 2;          // nrow in {256,64}: divisible by 4
    const float4* xb4 = (const float4*)(x + ((size_t)b * S_LEN + s0) * 9);
    const float4* pb4 = (const float4*)(pos + (size_t)s0 * 9);
    float4* ys4 = (float4*)ys[t];
    for (int i = tid; i < n4; i += TB) {
      float4 a = xb4[i], p = pb4[i];
      ys4[i] = make_float4(a.x + p.x, a.y + p.y, a.z + p.z, a.w + p.w);
    }
  }
  __syncthreads();  // staging + weights visible
#pragma unroll
  for (int t = 0; t < TPB; ++t) {
    if (tid < nrowA[t]) {
      float* r = &ys[t][tid * 9];
      float v[9], m = 0.f;
#pragma unroll
      for (int j = 0; j < 9; ++j) { v[j] = r[j]; m += v[j]; }
      m *= (1.f / 9.f);
      float var = 0.f;
#pragma unroll
      for (int j = 0; j < 9; ++j) { float d = v[j] - m; var += d * d; }
      var *= (1.f / 9.f);
      float rs = rsqrtf(var + 1e-6f);
#pragma unroll
      for (int j = 0; j < 9; ++j) r[j] = (v[j] - m) * rs * lgS[j] + lbS[j];
    }
  }
  // rows are thread-private (thread tid owns row tid of each tile): no sync needed

  // ---- phase 1: bind accumulation ----
  float acc[8];
#pragma unroll
  for (int i = 0; i < 8; ++i) acc[i] = 0.f;
#pragma unroll
  for (int t = 0; t < TPB; ++t) {
    if (tid < nrowA[t]) {
      const float* y = &ys[t][tid * 9];
      float kk[8], vv[8];
      matvec89(wkS, bkS, y, kk);
      matvec89(wvS, bvS, y, vv);
#pragma unroll
      for (int h = 0; h < 4; ++h) {
        float k0 = kk[2 * h], k1 = kk[2 * h + 1];
        float v0 = vv[2 * h], v1 = vv[2 * h + 1];
        acc[2 * h]     += k0 * v0 + k1 * v1;
        acc[2 * h + 1] += k0 * v1 + k1 * v0;
      }
    }
  }
#pragma unroll
  for (int i = 0; i < 8; ++i) {
#pragma unroll
    for (int off = 32; off > 0; off >>= 1) acc[i] += __shfl_down(acc[i], off, 64);
  }
  __syncthreads();
  if (lane == 0) {
#pragma unroll
    for (int i = 0; i < 8; ++i) red[wave * 8 + i] = acc[i];
  }
  __syncthreads();
  if (tid < 8) {
    float s = red[tid] + red[8 + tid] + red[16 + tid] + red[24 + tid];
    __hip_atomic_store(&bindP[bid * 8 + tid], s, __ATOMIC_RELAXED, __HIP_MEMORY_SCOPE_AGENT);
  }

  batch_barrier(&ctr1[b * CTRW], tid);

  if (tid < 8) {
    float s = 0.f;
#pragma unroll
    for (int j = 0; j < BPB; ++j)
      s += __hip_atomic_load(&bindP[((b * BPB + j)) * 8 + tid],
                             __ATOMIC_RELAXED, __HIP_MEMORY_SCOPE_AGENT);
    bindS[tid] = s;
  }
  __syncthreads();

  // ---- phase 2: softmax numerators (regs) + denominator partials ----
  float e[TPB][4];
  float esum[4] = {0.f, 0.f, 0.f, 0.f};
#pragma unroll
  for (int t = 0; t < TPB; ++t) {
    const int s0 = (t0 + t) * TB;
#pragma unroll
    for (int h = 0; h < 4; ++h) e[t][h] = 0.f;
    if (tid < nrowA[t]) {
      const int s = s0 + tid;
      const float* y = &ys[t][tid * 9];
      float qq[8], vv[8];
      matvec89(wqS, bqS, y, qq);
      matvec89(wvS, bvS, y, vv);
#pragma unroll
      for (int h = 0; h < 4; ++h) {
        float m = mask[((size_t)(b * 4 + h)) * S_LEN + s];
        e[t][h] = expf(head_scale(qq, vv, bindS, h, m));  // |cos sim|<=1: no max-sub
        esum[h] += e[t][h];
      }
    }
  }
#pragma unroll
  for (int h = 0; h < 4; ++h) {
#pragma unroll
    for (int off = 32; off > 0; off >>= 1) esum[h] += __shfl_down(esum[h], off, 64);
  }
  __syncthreads();
  if (lane == 0) {
#pragma unroll
    for (int h = 0; h < 4; ++h) red[wave * 4 + h] = esum[h];
  }
  __syncthreads();
  if (tid < 4) {
    float s = red[tid] + red[4 + tid] + red[8 + tid] + red[12 + tid];
    __hip_atomic_store(&sumPB[bid * 4 + tid], s, __ATOMIC_RELAXED, __HIP_MEMORY_SCOPE_AGENT);
  }

  batch_barrier(&ctr2[b * CTRW], tid);

  if (tid < 4) {
    float s = 0.f;
#pragma unroll
    for (int j = 0; j < BPB; ++j)
      s += __hip_atomic_load(&sumPB[((b * BPB + j)) * 4 + tid],
                             __ATOMIC_RELAXED, __HIP_MEMORY_SCOPE_AGENT);
    invDS[tid] = 1.f / s;
  }
  __syncthreads();

  // ---- phase 3: output ----
#pragma unroll
  for (int t = 0; t < TPB; ++t) {
    const int s0 = (t0 + t) * TB;
    if (tid < nrowA[t]) {
      const int s = s0 + tid;
      const float* y = &ys[t][tid * 9];
      float vv[8];
      matvec89(wvS, bvS, y, vv);
      float w0 = e[t][0] * invDS[0], w1 = e[t][1] * invDS[1];
      float w2 = e[t][2] * invDS[2], w3 = e[t][3] * invDS[3];
      float attn[8] = {w0 * vv[0], w0 * vv[1], w1 * vv[2], w1 * vv[3],
                       w2 * vv[4], w2 * vv[5], w3 * vv[6], w3 * vv[7]};
      float o = boS;
#pragma unroll
      for (int i = 0; i < 9; ++i) {
        float tt = b2S[i];
#pragma unroll
        for (int j = 0; j < 8; ++j) tt += w2S[i * 8 + j] * attn[j];
        float g = 0.5f * tt * (1.f + erff(tt * 0.70710678118654752f));
        o += woS[i] * (g + y[i]);
      }
      out[(size_t)b * S_LEN + s] = o;
    }
  }
}

// ---------------- launch ----------------

extern "C" void kernel_launch(void* const* d_in, const int* in_sizes, int n_in,
                              void* d_out, int out_size, void* d_ws, size_t ws_size,
                              hipStream_t stream) {
  const float* x    = (const float*)d_in[0];
  const float* mask = (const float*)d_in[1];
  const float* pos  = (const float*)d_in[2];
  const float* lng  = (const float*)d_in[3];
  const float* lnb  = (const float*)d_in[4];
  const float* Wq   = (const float*)d_in[5];
  const float* bq   = (const float*)d_in[6];
  const float* Wk   = (const float*)d_in[7];
  const float* bk   = (const float*)d_in[8];
  const float* Wv   = (const float*)d_in[9];
  const float* bv   = (const float*)d_in[10];
  // d_in[11] = W1, d_in[12] = b1 (dead in reference)
  const float* W2   = (const float*)d_in[13];
  const float* b2   = (const float*)d_in[14];
  const float* Wo   = (const float*)d_in[15];
  const float* bo   = (const float*)d_in[16];
  float* out = (float*)d_out;

  // ws layout: [ctr1: 128*16 u32][ctr2: 128*16 u32][bindP: 1024*8 f32][sumPB: 1024*4 f32]
  unsigned* ctr1  = (unsigned*)d_ws;
  unsigned* ctr2  = ctr1 + B_N * CTRW;
  float*    bindP = (float*)(ctr2 + B_N * CTRW);
  float*    sumPB = bindP + GRID * 8;

  hipMemsetAsync(d_ws, 0, 2 * B_N * CTRW * sizeof(unsigned), stream);
  k_fused<<<GRID, TB, 0, stream>>>(x, mask, pos, lng, lnb, Wq, bq, Wk, bk, Wv, bv,
                                   W2, b2, Wo, bo, ctr1, ctr2, bindP, sumPB, out);
}

// Round 6
// 78.833 us; speedup vs baseline: 2.0963x; 1.7781x over previous
//
#include <hip/hip_runtime.h>
#include <math.h>

#define TB 256
#define S_LEN 8000
#define B_N 128
#define BPB 8            // sibling blocks per batch (share the two reductions)
#define TPB 4            // 256-row tiles per block: 8*4*256 >= 8000
#define GRID (B_N * BPB) // 1024 blocks; co-resident at >=4 blocks/CU (guaranteed by launch_bounds)
#define CTRW 32          // uints per counter slot (128 B padding)

// ---------------- device helpers ----------------

__device__ __forceinline__ void ln_row(const float* __restrict__ r,
                                       const float* __restrict__ lg, const float* __restrict__ lb,
                                       float* y) {
  float v[9], m = 0.f;
#pragma unroll
  for (int j = 0; j < 9; ++j) { v[j] = r[j]; m += v[j]; }
  m *= (1.f / 9.f);
  float var = 0.f;
#pragma unroll
  for (int j = 0; j < 9; ++j) { float d = v[j] - m; var += d * d; }
  var *= (1.f / 9.f);
  float rs = rsqrtf(var + 1e-6f);
#pragma unroll
  for (int j = 0; j < 9; ++j) y[j] = (v[j] - m) * rs * lg[j] + lb[j];
}

__device__ __forceinline__ void matvec89(const float* __restrict__ W, const float* __restrict__ bias,
                                         const float* __restrict__ y, float* out) {
#pragma unroll
  for (int i = 0; i < 8; ++i) {
    float a = bias[i];
#pragma unroll
    for (int j = 0; j < 9; ++j) a += W[i * 9 + j] * y[j];
    out[i] = a;
  }
}

__device__ __forceinline__ float head_scale(const float* q, const float* v, const float* bindS,
                                            int h, float maskv) {
  float q0 = q[2 * h], q1 = q[2 * h + 1];
  float v0 = v[2 * h], v1 = v[2 * h + 1];
  float B0 = bindS[2 * h], B1 = bindS[2 * h + 1];
  // HD=2: real 2-pt FFT self-conjugate -> unbinding == circular conv
  float vp0 = B0 * q0 + B1 * q1;
  float vp1 = B0 * q1 + B1 * q0;
  float num = v0 * vp0 + v1 * vp1;
  float na = fmaxf(sqrtf(v0 * v0 + v1 * v1), 1e-8f);
  float nb = fmaxf(sqrtf(vp0 * vp0 + vp1 * vp1), 1e-8f);
  float sc = num / (na * nb);
  sc += (1.f - maskv) * (-1e9f);
  return sc;
}

// qq,vv + per-head softmax numerators for one row (used by phases 2 and 3)
__device__ __forceinline__ void row_e(const float* __restrict__ y,
                                      const float* __restrict__ wqS, const float* __restrict__ bqS,
                                      const float* __restrict__ wvS, const float* __restrict__ bvS,
                                      const float* __restrict__ bindS,
                                      const float* __restrict__ maskb, int s,
                                      float* vv, float* e) {
  float qq[8];
  matvec89(wqS, bqS, y, qq);
  matvec89(wvS, bvS, y, vv);
#pragma unroll
  for (int h = 0; h < 4; ++h) {
    float m = maskb[(size_t)h * S_LEN + s];
    e[h] = __expf(head_scale(qq, vv, bindS, h, m));  // |cos sim|<=1: no max-sub needed
  }
}

__device__ __forceinline__ void stage_x(const float* __restrict__ x, const float* __restrict__ pos,
                                        int b, int s0, int nrow, float4* xs4, int tid) {
  const int n4 = (nrow * 9) >> 2;   // nrow in {256,64}: nrow*9 divisible by 4
  const float4* xb4 = (const float4*)(x + ((size_t)b * S_LEN + s0) * 9);
  const float4* pb4 = (const float4*)(pos + (size_t)s0 * 9);
  for (int i = tid; i < n4; i += TB) {
    float4 a = xb4[i], p = pb4[i];
    xs4[i] = make_float4(a.x + p.x, a.y + p.y, a.z + p.z, a.w + p.w);
  }
}

// Per-batch barrier among BPB siblings. FULLY RELAXED: the arrival RMW and the
// poll are relaxed agent atomics (served at the coherence point, no cache
// maintenance). Ordering: __syncthreads drains vmcnt, so the sibling's relaxed
// agent-atomic data stores completed at the LLC before its arrival add.
__device__ __forceinline__ void batch_barrier(unsigned* ctr, int tid) {
  __syncthreads();
  if (tid == 0) {
    __hip_atomic_fetch_add(ctr, 1u, __ATOMIC_RELAXED, __HIP_MEMORY_SCOPE_AGENT);
    while (__hip_atomic_load(ctr, __ATOMIC_RELAXED, __HIP_MEMORY_SCOPE_AGENT) < (unsigned)BPB)
      __builtin_amdgcn_s_sleep(8);
  }
  __syncthreads();
}

// ---------------- fused kernel ----------------
__global__ __launch_bounds__(TB, 4) void k_fused(
    const float* __restrict__ x, const float* __restrict__ mask, const float* __restrict__ pos,
    const float* __restrict__ lng, const float* __restrict__ lnb,
    const float* __restrict__ Wq, const float* __restrict__ bq,
    const float* __restrict__ Wk, const float* __restrict__ bk,
    const float* __restrict__ Wv, const float* __restrict__ bv,
    const float* __restrict__ W2, const float* __restrict__ b2,
    const float* __restrict__ Wo, const float* __restrict__ bo,
    unsigned* __restrict__ ctr1, unsigned* __restrict__ ctr2,
    float* __restrict__ bindP, float* __restrict__ sumP,
    float* __restrict__ out) {
  __shared__ float4 xs4[TB * 9 / 4];   // 9.2 KB staging tile (re-staged per phase)
  __shared__ float wqS[72], wkS[72], wvS[72], w2S[72];
  __shared__ float bqS[8], bkS[8], bvS[8], b2S[9], woS[9], lgS[9], lbS[9];
  __shared__ float boS;
  __shared__ float red[4 * 8];
  __shared__ float bindS[8], invDS[4];
  float* xs = (float*)xs4;

  const int tid = threadIdx.x, bid = blockIdx.x;
  const int b = bid >> 3;            // batch 0..127
  const int t0 = (bid & 7) * TPB;    // first tile (0,4,...,28)
  const int wave = tid >> 6, lane = tid & 63;
  const float* maskb = mask + (size_t)b * 4 * S_LEN;

  if (tid < 72) { wqS[tid] = Wq[tid]; wkS[tid] = Wk[tid]; wvS[tid] = Wv[tid]; w2S[tid] = W2[tid]; }
  if (tid < 8)  { bqS[tid] = bq[tid]; bkS[tid] = bk[tid]; bvS[tid] = bv[tid]; }
  if (tid < 9)  { lgS[tid] = lng[tid]; lbS[tid] = lnb[tid]; b2S[tid] = b2[tid]; woS[tid] = Wo[tid]; }
  if (tid == 0) { boS = bo[0]; }

  // ---- phase 1: bind accumulation ----
  float acc[8];
#pragma unroll
  for (int i = 0; i < 8; ++i) acc[i] = 0.f;
#pragma unroll
  for (int t = 0; t < TPB; ++t) {
    const int s0 = (t0 + t) * TB;
    const int nrow = min(TB, S_LEN - s0);
    __syncthreads();
    stage_x(x, pos, b, s0, nrow, xs4, tid);
    __syncthreads();
    if (tid < nrow) {
      float y[9];
      ln_row(&xs[tid * 9], lgS, lbS, y);
      float kk[8], vv[8];
      matvec89(wkS, bkS, y, kk);
      matvec89(wvS, bvS, y, vv);
#pragma unroll
      for (int h = 0; h < 4; ++h) {
        float k0 = kk[2 * h], k1 = kk[2 * h + 1];
        float v0 = vv[2 * h], v1 = vv[2 * h + 1];
        acc[2 * h]     += k0 * v0 + k1 * v1;
        acc[2 * h + 1] += k0 * v1 + k1 * v0;
      }
    }
  }
#pragma unroll
  for (int i = 0; i < 8; ++i) {
#pragma unroll
    for (int off = 32; off > 0; off >>= 1) acc[i] += __shfl_down(acc[i], off, 64);
  }
  __syncthreads();
  if (lane == 0) {
#pragma unroll
    for (int i = 0; i < 8; ++i) red[wave * 8 + i] = acc[i];
  }
  __syncthreads();
  if (tid < 8) {
    float s = red[tid] + red[8 + tid] + red[16 + tid] + red[24 + tid];
    __hip_atomic_store(&bindP[bid * 8 + tid], s, __ATOMIC_RELAXED, __HIP_MEMORY_SCOPE_AGENT);
  }

  batch_barrier(&ctr1[b * CTRW], tid);

  if (tid < 8) {
    float s = 0.f;
#pragma unroll
    for (int j = 0; j < BPB; ++j)
      s += __hip_atomic_load(&bindP[(b * BPB + j) * 8 + tid],
                             __ATOMIC_RELAXED, __HIP_MEMORY_SCOPE_AGENT);
    bindS[tid] = s;
  }
  // published by the first __syncthreads of the phase-2 tile loop

  // ---- phase 2: softmax denominator partials ----
  float esum[4] = {0.f, 0.f, 0.f, 0.f};
#pragma unroll
  for (int t = 0; t < TPB; ++t) {
    const int s0 = (t0 + t) * TB;
    const int nrow = min(TB, S_LEN - s0);
    __syncthreads();
    stage_x(x, pos, b, s0, nrow, xs4, tid);
    __syncthreads();
    if (tid < nrow) {
      float y[9];
      ln_row(&xs[tid * 9], lgS, lbS, y);
      float vv[8], e[4];
      row_e(y, wqS, bqS, wvS, bvS, bindS, maskb, s0 + tid, vv, e);
#pragma unroll
      for (int h = 0; h < 4; ++h) esum[h] += e[h];
    }
  }
#pragma unroll
  for (int h = 0; h < 4; ++h) {
#pragma unroll
    for (int off = 32; off > 0; off >>= 1) esum[h] += __shfl_down(esum[h], off, 64);
  }
  __syncthreads();
  if (lane == 0) {
#pragma unroll
    for (int h = 0; h < 4; ++h) red[wave * 4 + h] = esum[h];
  }
  __syncthreads();
  if (tid < 4) {
    float s = red[tid] + red[4 + tid] + red[8 + tid] + red[12 + tid];
    __hip_atomic_store(&sumP[bid * 4 + tid], s, __ATOMIC_RELAXED, __HIP_MEMORY_SCOPE_AGENT);
  }

  batch_barrier(&ctr2[b * CTRW], tid);

  if (tid < 4) {
    float s = 0.f;
#pragma unroll
    for (int j = 0; j < BPB; ++j)
      s += __hip_atomic_load(&sumP[(b * BPB + j) * 4 + tid],
                             __ATOMIC_RELAXED, __HIP_MEMORY_SCOPE_AGENT);
    invDS[tid] = 1.f / s;
  }
  // published by the first __syncthreads of the phase-3 tile loop

  // ---- phase 3: output (recompute e: zero state carried across barriers) ----
#pragma unroll
  for (int t = 0; t < TPB; ++t) {
    const int s0 = (t0 + t) * TB;
    const int nrow = min(TB, S_LEN - s0);
    __syncthreads();
    stage_x(x, pos, b, s0, nrow, xs4, tid);
    __syncthreads();
    if (tid < nrow) {
      const int s = s0 + tid;
      float y[9];
      ln_row(&xs[tid * 9], lgS, lbS, y);
      float vv[8], e[4];
      row_e(y, wqS, bqS, wvS, bvS, bindS, maskb, s, vv, e);
      float w0 = e[0] * invDS[0], w1 = e[1] * invDS[1];
      float w2 = e[2] * invDS[2], w3 = e[3] * invDS[3];
      float attn[8] = {w0 * vv[0], w0 * vv[1], w1 * vv[2], w1 * vv[3],
                       w2 * vv[4], w2 * vv[5], w3 * vv[6], w3 * vv[7]};
      float o = boS;
#pragma unroll
      for (int i = 0; i < 9; ++i) {
        float tt = b2S[i];
#pragma unroll
        for (int j = 0; j < 8; ++j) tt += w2S[i * 8 + j] * attn[j];
        float g = 0.5f * tt * (1.f + erff(tt * 0.70710678118654752f));
        o += woS[i] * (g + y[i]);
      }
      out[(size_t)b * S_LEN + s] = o;
    }
  }
}

// ---------------- launch ----------------

extern "C" void kernel_launch(void* const* d_in, const int* in_sizes, int n_in,
                              void* d_out, int out_size, void* d_ws, size_t ws_size,
                              hipStream_t stream) {
  const float* x    = (const float*)d_in[0];
  const float* mask = (const float*)d_in[1];
  const float* pos  = (const float*)d_in[2];
  const float* lng  = (const float*)d_in[3];
  const float* lnb  = (const float*)d_in[4];
  const float* Wq   = (const float*)d_in[5];
  const float* bq   = (const float*)d_in[6];
  const float* Wk   = (const float*)d_in[7];
  const float* bk   = (const float*)d_in[8];
  const float* Wv   = (const float*)d_in[9];
  const float* bv   = (const float*)d_in[10];
  // d_in[11] = W1, d_in[12] = b1 (dead in reference)
  const float* W2   = (const float*)d_in[13];
  const float* b2   = (const float*)d_in[14];
  const float* Wo   = (const float*)d_in[15];
  const float* bo   = (const float*)d_in[16];
  float* out = (float*)d_out;

  // ws: [ctr1 128*32 u32][ctr2 128*32 u32][bindP 1024*8 f32][sumP 1024*4 f32]
  unsigned* ctr1  = (unsigned*)d_ws;
  unsigned* ctr2  = ctr1 + B_N * CTRW;
  float*    bindP = (float*)(ctr2 + B_N * CTRW);
  float*    sumP  = bindP + GRID * 8;

  hipMemsetAsync(d_ws, 0, 2 * B_N * CTRW * sizeof(unsigned), stream);
  k_fused<<<GRID, TB, 0, stream>>>(x, mask, pos, lng, lnb, Wq, bq, Wk, bk, Wv, bv,
                                   W2, b2, Wo, bo, ctr1, ctr2, bindP, sumP, out);
}

// Round 7
// 42.815 us; speedup vs baseline: 3.8599x; 1.8413x over previous
//
#include <hip/hip_runtime.h>
#include <math.h>

#define TB 256
#define S_LEN 8000
#define B_N 128
#define BPB 8            // sibling blocks per batch (share the two reductions)
#define TPB 4            // 256-row tiles per block: 8*4*256 >= 8000
#define GRID (B_N * BPB) // 1024 blocks, all co-resident at 4 blocks/CU
#define CTRW 32          // uints per counter slot (128 B padding)

// ---------------- device helpers ----------------

// erf via Taylor for |z|<0.5 (err < 1e-5); provably |z|<<0.5 here (softmax
// weights <= e^2/8000 => |t| < 0.1), erff fallback never taken in practice.
__device__ __forceinline__ float erf_fast(float z) {
  float z2 = z * z;
  if (__builtin_expect(z2 > 0.25f, 0)) return erff(z);
  const float c0 = 1.1283791670955126f;  // 2/sqrt(pi)
  return c0 * z * (1.f + z2 * (-1.f / 3.f + z2 * (0.1f - z2 * (1.f / 42.f))));
}

// matvec8x9 reading W/bias straight from global: uniform pointer + constant
// indices -> scalar loads (SGPR operands), zero VALU/LDS overhead.
__device__ __forceinline__ void matvec89(const float* __restrict__ W, const float* __restrict__ bias,
                                         const float* __restrict__ y, float* out) {
#pragma unroll
  for (int i = 0; i < 8; ++i) {
    float a = bias[i];
#pragma unroll
    for (int j = 0; j < 9; ++j) a += W[i * 9 + j] * y[j];
    out[i] = a;
  }
}

__device__ __forceinline__ float head_scale(const float* q, const float* v, const float* bindS,
                                            int h, float maskv) {
  float q0 = q[2 * h], q1 = q[2 * h + 1];
  float v0 = v[2 * h], v1 = v[2 * h + 1];
  float B0 = bindS[2 * h], B1 = bindS[2 * h + 1];
  // HD=2: real 2-pt FFT self-conjugate -> unbinding == circular conv
  float vp0 = B0 * q0 + B1 * q1;
  float vp1 = B0 * q1 + B1 * q0;
  float num = v0 * vp0 + v1 * vp1;
  // max(sqrt(a2),1e-8) == sqrt(max(a2,1e-16)) -> rsqrt form, no sqrt/div
  float a2 = fmaxf(v0 * v0 + v1 * v1, 1e-16f);
  float b2 = fmaxf(vp0 * vp0 + vp1 * vp1, 1e-16f);
  float sc = num * rsqrtf(a2) * rsqrtf(b2);
  sc += (1.f - maskv) * (-1e9f);
  return sc;
}

// Per-batch barrier among BPB siblings: fully RELAXED agent atomics (served at
// the coherence point, no cache maintenance). Ordering: __syncthreads drains
// vmcnt, so sibling data stores hit the LLC before the arrival add. (validated r6)
__device__ __forceinline__ void batch_barrier(unsigned* ctr, int tid) {
  __syncthreads();
  if (tid == 0) {
    __hip_atomic_fetch_add(ctr, 1u, __ATOMIC_RELAXED, __HIP_MEMORY_SCOPE_AGENT);
    while (__hip_atomic_load(ctr, __ATOMIC_RELAXED, __HIP_MEMORY_SCOPE_AGENT) < (unsigned)BPB)
      __builtin_amdgcn_s_sleep(8);
  }
  __syncthreads();
}

// ---------------- fused kernel ----------------
__global__ __launch_bounds__(TB, 4) void k_fused(
    const float* __restrict__ x, const float* __restrict__ mask, const float* __restrict__ pos,
    const float* __restrict__ lng, const float* __restrict__ lnb,
    const float* __restrict__ Wq, const float* __restrict__ bq,
    const float* __restrict__ Wk, const float* __restrict__ bk,
    const float* __restrict__ Wv, const float* __restrict__ bv,
    const float* __restrict__ W2, const float* __restrict__ b2,
    const float* __restrict__ Wo, const float* __restrict__ bo,
    unsigned* __restrict__ ctr1, unsigned* __restrict__ ctr2,
    float* __restrict__ bindP, float* __restrict__ sumP,
    float* __restrict__ out) {
  __shared__ float ys[TPB][TB * 9];   // LN output, resident all phases (36.9 KB)
  __shared__ float red[4 * 8];
  __shared__ float bindS[8], invDS[4];

  const int tid = threadIdx.x, bid = blockIdx.x;
  const int b = bid >> 3;            // batch 0..127
  const int t0 = (bid & 7) * TPB;    // first tile (0,4,...,28)
  const int wave = tid >> 6, lane = tid & 63;
  const float* maskb = mask + (size_t)b * 4 * S_LEN;

  int nrowA[TPB];
#pragma unroll
  for (int t = 0; t < TPB; ++t) nrowA[t] = min(TB, S_LEN - (t0 + t) * TB);

  // ---- phase 0: stage x+pos once (float4), LayerNorm in place ----
#pragma unroll
  for (int t = 0; t < TPB; ++t) {
    const int s0 = (t0 + t) * TB;
    const int n4 = (nrowA[t] * 9) >> 2;           // nrow in {256,64}: divisible by 4
    const float4* xb4 = (const float4*)(x + ((size_t)b * S_LEN + s0) * 9);
    const float4* pb4 = (const float4*)(pos + (size_t)s0 * 9);
    float4* ys4 = (float4*)ys[t];
    for (int i = tid; i < n4; i += TB) {
      float4 a = xb4[i], p = pb4[i];
      ys4[i] = make_float4(a.x + p.x, a.y + p.y, a.z + p.z, a.w + p.w);
    }
  }
  __syncthreads();
#pragma unroll
  for (int t = 0; t < TPB; ++t) {
    if (tid < nrowA[t]) {
      float* r = &ys[t][tid * 9];
      float v[9], m = 0.f;
#pragma unroll
      for (int j = 0; j < 9; ++j) { v[j] = r[j]; m += v[j]; }
      m *= (1.f / 9.f);
      float var = 0.f;
#pragma unroll
      for (int j = 0; j < 9; ++j) { float d = v[j] - m; var += d * d; }
      var *= (1.f / 9.f);
      float rs = rsqrtf(var + 1e-6f);
#pragma unroll
      for (int j = 0; j < 9; ++j) r[j] = (v[j] - m) * rs * lng[j] + lnb[j];
    }
  }
  // rows are thread-private after this point: no sync needed before reads

  // ---- phase 1: k,v matvecs; vv kept in regs; bind accumulation ----
  float vv[TPB][8];   // held across both barriers (32 VGPR, static indexing)
  float acc[8];
#pragma unroll
  for (int i = 0; i < 8; ++i) acc[i] = 0.f;
#pragma unroll
  for (int t = 0; t < TPB; ++t) {
    if (tid < nrowA[t]) {
      const float* y = &ys[t][tid * 9];
      float kk[8];
      matvec89(Wk, bk, y, kk);
      matvec89(Wv, bv, y, vv[t]);
#pragma unroll
      for (int h = 0; h < 4; ++h) {
        float k0 = kk[2 * h], k1 = kk[2 * h + 1];
        float v0 = vv[t][2 * h], v1 = vv[t][2 * h + 1];
        acc[2 * h]     += k0 * v0 + k1 * v1;
        acc[2 * h + 1] += k0 * v1 + k1 * v0;
      }
    }
  }
#pragma unroll
  for (int i = 0; i < 8; ++i) {
#pragma unroll
    for (int off = 32; off > 0; off >>= 1) acc[i] += __shfl_down(acc[i], off, 64);
  }
  __syncthreads();
  if (lane == 0) {
#pragma unroll
    for (int i = 0; i < 8; ++i) red[wave * 8 + i] = acc[i];
  }
  __syncthreads();
  if (tid < 8) {
    float s = red[tid] + red[8 + tid] + red[16 + tid] + red[24 + tid];
    __hip_atomic_store(&bindP[bid * 8 + tid], s, __ATOMIC_RELAXED, __HIP_MEMORY_SCOPE_AGENT);
  }

  batch_barrier(&ctr1[b * CTRW], tid);

  if (tid < 8) {
    float s = 0.f;
#pragma unroll
    for (int j = 0; j < BPB; ++j)
      s += __hip_atomic_load(&bindP[(b * BPB + j) * 8 + tid],
                             __ATOMIC_RELAXED, __HIP_MEMORY_SCOPE_AGENT);
    bindS[tid] = s;
  }
  __syncthreads();

  // ---- phase 2: q matvec + e numerators (regs) + denominator partials ----
  float e[TPB][4];
  float esum[4] = {0.f, 0.f, 0.f, 0.f};
#pragma unroll
  for (int t = 0; t < TPB; ++t) {
    const int s0 = (t0 + t) * TB;
#pragma unroll
    for (int h = 0; h < 4; ++h) e[t][h] = 0.f;
    if (tid < nrowA[t]) {
      const float* y = &ys[t][tid * 9];
      float qq[8];
      matvec89(Wq, bq, y, qq);
#pragma unroll
      for (int h = 0; h < 4; ++h) {
        float m = maskb[(size_t)h * S_LEN + s0 + tid];
        e[t][h] = __expf(head_scale(qq, vv[t], bindS, h, m));  // |cos|<=1: no max-sub
        esum[h] += e[t][h];
      }
    }
  }
#pragma unroll
  for (int h = 0; h < 4; ++h) {
#pragma unroll
    for (int off = 32; off > 0; off >>= 1) esum[h] += __shfl_down(esum[h], off, 64);
  }
  __syncthreads();
  if (lane == 0) {
#pragma unroll
    for (int h = 0; h < 4; ++h) red[wave * 4 + h] = esum[h];
  }
  __syncthreads();
  if (tid < 4) {
    float s = red[tid] + red[4 + tid] + red[8 + tid] + red[12 + tid];
    __hip_atomic_store(&sumP[bid * 4 + tid], s, __ATOMIC_RELAXED, __HIP_MEMORY_SCOPE_AGENT);
  }

  batch_barrier(&ctr2[b * CTRW], tid);

  if (tid < 4) {
    float s = 0.f;
#pragma unroll
    for (int j = 0; j < BPB; ++j)
      s += __hip_atomic_load(&sumP[(b * BPB + j) * 4 + tid],
                             __ATOMIC_RELAXED, __HIP_MEMORY_SCOPE_AGENT);
    invDS[tid] = 1.f / s;
  }
  __syncthreads();

  // ---- phase 3: attn from regs, FFN (poly-erf gelu), output ----
#pragma unroll
  for (int t = 0; t < TPB; ++t) {
    const int s0 = (t0 + t) * TB;
    if (tid < nrowA[t]) {
      const float* y = &ys[t][tid * 9];
      float w0 = e[t][0] * invDS[0], w1 = e[t][1] * invDS[1];
      float w2 = e[t][2] * invDS[2], w3 = e[t][3] * invDS[3];
      float attn[8] = {w0 * vv[t][0], w0 * vv[t][1], w1 * vv[t][2], w1 * vv[t][3],
                       w2 * vv[t][4], w2 * vv[t][5], w3 * vv[t][6], w3 * vv[t][7]};
      float o = bo[0];
#pragma unroll
      for (int i = 0; i < 9; ++i) {
        float tt = b2[i];
#pragma unroll
        for (int j = 0; j < 8; ++j) tt += W2[i * 8 + j] * attn[j];
        float g = 0.5f * tt * (1.f + erf_fast(tt * 0.70710678118654752f));
        o += Wo[i] * (g + y[i]);
      }
      out[(size_t)b * S_LEN + s0 + tid] = o;
    }
  }
}

// ---------------- launch ----------------

extern "C" void kernel_launch(void* const* d_in, const int* in_sizes, int n_in,
                              void* d_out, int out_size, void* d_ws, size_t ws_size,
                              hipStream_t stream) {
  const float* x    = (const float*)d_in[0];
  const float* mask = (const float*)d_in[1];
  const float* pos  = (const float*)d_in[2];
  const float* lng  = (const float*)d_in[3];
  const float* lnb  = (const float*)d_in[4];
  const float* Wq   = (const float*)d_in[5];
  const float* bq   = (const float*)d_in[6];
  const float* Wk   = (const float*)d_in[7];
  const float* bk   = (const float*)d_in[8];
  const float* Wv   = (const float*)d_in[9];
  const float* bv   = (const float*)d_in[10];
  // d_in[11] = W1, d_in[12] = b1 (dead in reference)
  const float* W2   = (const float*)d_in[13];
  const float* b2   = (const float*)d_in[14];
  const float* Wo   = (const float*)d_in[15];
  const float* bo   = (const float*)d_in[16];
  float* out = (float*)d_out;

  // ws: [ctr1 128*32 u32][ctr2 128*32 u32][bindP 1024*8 f32][sumP 1024*4 f32]
  unsigned* ctr1  = (unsigned*)d_ws;
  unsigned* ctr2  = ctr1 + B_N * CTRW;
  float*    bindP = (float*)(ctr2 + B_N * CTRW);
  float*    sumP  = bindP + GRID * 8;

  hipMemsetAsync(d_ws, 0, 2 * B_N * CTRW * sizeof(unsigned), stream);
  k_fused<<<GRID, TB, 0, stream>>>(x, mask, pos, lng, lnb, Wq, bq, Wk, bk, Wv, bv,
                                   W2, b2, Wo, bo, ctr1, ctr2, bindP, sumP, out);
}